// Round 7
// baseline (1458.440 us; speedup 1.0000x reference)
//
#include <hip/hip_runtime.h>

#define E_EDGES 262144
#define V_NODES 65536
#define D_DIM   256

typedef short bf16x8 __attribute__((ext_vector_type(8)));
typedef float f32x4  __attribute__((ext_vector_type(4)));

__device__ __forceinline__ unsigned short f2bf(float f) {
  union { float f; unsigned u; } x; x.f = f;
  unsigned r = x.u + 0x7FFFu + ((x.u >> 16) & 1u);
  return (unsigned short)(r >> 16);
}
__device__ __forceinline__ float bf2f(unsigned short h) {
  union { unsigned u; float f; } x; x.u = ((unsigned)h) << 16;
  return x.f;
}
__device__ __forceinline__ void async16(const void* g, void* l) {
  __builtin_amdgcn_global_load_lds(
      (const __attribute__((address_space(1))) unsigned*)g,
      (__attribute__((address_space(3))) unsigned*)l, 16, 0, 0);
}

// ---------------- weight convert + transpose to bf16 [N][K] ----------------
__global__ __launch_bounds__(256) void convert_weights_kernel(
    const float* __restrict__ W1, const float* __restrict__ W2,
    unsigned short* __restrict__ W1T, unsigned short* __restrict__ W2T) {
  int idx = blockIdx.x * 256 + threadIdx.x;           // 0 .. 655359
  {
    int k = idx & 255, n = (idx >> 8) & 511, i = idx >> 17;
    W1T[idx] = f2bf(W1[((size_t)(i * 256 + k)) * 512 + n]);
  }
  {
    int k = idx & 511, n = (idx >> 9) & 255, i = idx >> 17;
    W2T[idx] = f2bf(W2[((size_t)(i * 512 + k)) * 256 + n]);
  }
}

// ---------------- CSR build (by destination) ----------------
__global__ void hist_kernel(const int* __restrict__ ei, int* __restrict__ counts) {
  int e = blockIdx.x * 256 + threadIdx.x;
  int d = (e < E_EDGES) ? ei[E_EDGES + e] : (e - E_EDGES);
  atomicAdd(&counts[d], 1);
}
__global__ void scan1_kernel(const int* __restrict__ counts, int* __restrict__ indptr,
                             int* __restrict__ bsums) {
  __shared__ int s[256];
  int t = threadIdx.x, b = blockIdx.x;
  int v = counts[b * 256 + t];
  s[t] = v; __syncthreads();
  for (int off = 1; off < 256; off <<= 1) {
    int add = (t >= off) ? s[t - off] : 0;
    __syncthreads();
    s[t] += add;
    __syncthreads();
  }
  indptr[b * 256 + t] = s[t] - v;
  if (t == 255) bsums[b] = s[255];
}
__global__ void scan2_kernel(const int* __restrict__ bsums, int* __restrict__ boff) {
  __shared__ int s[256];
  int t = threadIdx.x;
  int v = bsums[t];
  s[t] = v; __syncthreads();
  for (int off = 1; off < 256; off <<= 1) {
    int add = (t >= off) ? s[t - off] : 0;
    __syncthreads();
    s[t] += add;
    __syncthreads();
  }
  boff[t] = s[t] - v;
}
__global__ void scan3_kernel(int* __restrict__ indptr, const int* __restrict__ boff) {
  int t = threadIdx.x, b = blockIdx.x;
  indptr[b * 256 + t] += boff[b];
  if (b == 0 && t == 0) indptr[V_NODES] = E_EDGES + V_NODES;
}
__global__ void scatter_kernel(const int* __restrict__ ei, const int* __restrict__ indptr,
                               int* __restrict__ fill, int* __restrict__ csr_eid) {
  int e = blockIdx.x * 256 + threadIdx.x;
  int d = (e < E_EDGES) ? ei[E_EDGES + e] : (e - E_EDGES);
  int pos = indptr[d] + atomicAdd(&fill[d], 1);
  csr_eid[pos] = e;
}

// ---------------- message passing (v1 + 1-deep metadata pipeline) ----------------
// aggr = (1+eps)*h + sum relu(h[src]+eemb)*w   (fp32 out)
// h = x (L0) or relu(z2c*scale2 + shift2) with z2c centered bf16, shift2 = bb2.
template <bool L0>
__device__ __forceinline__ void load_hnorm(int node, int c0, const float* __restrict__ x,
                                           const unsigned short* __restrict__ hprev,
                                           const float* sc, const float* sh, float* out) {
  if (L0) {
    const float* p = x + ((size_t)((node >> 8) * 257 + (node & 255) + 1)) * 256 + c0;
    float4 tv = *(const float4*)p;
    out[0] = tv.x; out[1] = tv.y; out[2] = tv.z; out[3] = tv.w;
  } else {
    ushort4 tv = *(const ushort4*)(hprev + (size_t)node * 256 + c0);
    out[0] = fmaxf(bf2f(tv.x) * sc[0] + sh[0], 0.f);
    out[1] = fmaxf(bf2f(tv.y) * sc[1] + sh[1], 0.f);
    out[2] = fmaxf(bf2f(tv.z) * sc[2] + sh[2], 0.f);
    out[3] = fmaxf(bf2f(tv.w) * sc[3] + sh[3], 0.f);
  }
}

template <bool L0>
__global__ __launch_bounds__(256) void msg_kernel(
    const float* __restrict__ x, const unsigned short* __restrict__ hprev,
    const float* __restrict__ scale2, const float* __restrict__ shift2,
    const int* __restrict__ indptr, const int* __restrict__ csr_eid,
    const int* __restrict__ ei, const int* __restrict__ ea, const float* __restrict__ ew,
    const float* __restrict__ bemb, const float* __restrict__ eps_param, int layer,
    float* __restrict__ aggr_f) {
  int wid = threadIdx.x >> 6;
  int lane = threadIdx.x & 63;
  int v = blockIdx.x * 4 + wid;
  int c0 = lane * 4;
  float ep = 1.0f + eps_param[layer];

  float sc[4], sh[4];
  if (!L0) {
#pragma unroll
    for (int j = 0; j < 4; ++j) { sc[j] = scale2[c0 + j]; sh[j] = shift2[c0 + j]; }
  }

  float hv[4];
  load_hnorm<L0>(v, c0, x, hprev, sc, sh, hv);
  float acc[4] = { ep * hv[0], ep * hv[1], ep * hv[2], ep * hv[3] };

  int beg = indptr[v], end = indptr[v + 1];
  // resolve edge "beg" metadata up-front (degree >= 1 always: self-loops)
  int eid = csr_eid[beg];
  int s, a0, a1, a2; float w;
  if (eid < E_EDGES) {
    s = ei[eid]; a0 = ea[eid * 3]; a1 = ea[eid * 3 + 1]; a2 = ea[eid * 3 + 2]; w = ew[eid];
  } else { s = eid - E_EDGES; a0 = 5; a1 = 7; a2 = 0; w = 1.0f; }

  for (int p = beg; p < end; ++p) {
    // issue current edge's long-latency gathers FIRST
    float hs[4];
    load_hnorm<L0>(s, c0, x, hprev, sc, sh, hs);
    float4 e0 = *(const float4*)(bemb + (size_t)(a0) * 256 + c0);
    float4 e1 = *(const float4*)(bemb + (size_t)(16 + a1) * 256 + c0);
    float4 e2 = *(const float4*)(bemb + (size_t)(32 + a2) * 256 + c0);
    float wc = w;

    // overlap: resolve NEXT edge's metadata chain while gathers are in flight
    if (p + 1 < end) {
      int eidn = csr_eid[p + 1];
      if (eidn < E_EDGES) {
        s = ei[eidn]; a0 = ea[eidn * 3]; a1 = ea[eidn * 3 + 1]; a2 = ea[eidn * 3 + 2];
        w = ew[eidn];
      } else { s = eidn - E_EDGES; a0 = 5; a1 = 7; a2 = 0; w = 1.0f; }
    }

    acc[0] += fmaxf(hs[0] + e0.x + e1.x + e2.x, 0.f) * wc;
    acc[1] += fmaxf(hs[1] + e0.y + e1.y + e2.y, 0.f) * wc;
    acc[2] += fmaxf(hs[2] + e0.z + e1.z + e2.z, 0.f) * wc;
    acc[3] += fmaxf(hs[3] + e0.w + e1.w + e2.w, 0.f) * wc;
  }
  float4 o; o.x = acc[0]; o.y = acc[1]; o.z = acc[2]; o.w = acc[3];
  *(float4*)(aggr_f + (size_t)v * 256 + c0) = o;
}

// ---------------- column sums of fp32 aggr (for BN-invariant centering) ----------------
__global__ __launch_bounds__(256) void colsum_kernel(const float* __restrict__ aggr_f,
                                                     float* __restrict__ colsum) {
  int t = threadIdx.x;
  size_t base = (size_t)blockIdx.x * 64 * 256 + t;
  float s = 0.f;
#pragma unroll
  for (int r = 0; r < 64; ++r) s += aggr_f[base + (size_t)r * 256];
  atomicAdd(&colsum[t], s);
}

// ---------------- center columns + convert to bf16 (BN shift-invariance makes this exact) ----------------
__global__ __launch_bounds__(256) void center_kernel(const float* __restrict__ aggr_f,
                                                     const float* __restrict__ colsum,
                                                     unsigned short* __restrict__ aggr_c) {
  size_t i = ((size_t)blockIdx.x * 256 + threadIdx.x) * 4;
  int c = (int)(i & 255);
  float4 v = *(const float4*)(aggr_f + i);
  const float inv = 1.0f / 65536.0f;
  ushort4 o;
  o.x = f2bf(v.x - colsum[c + 0] * inv);
  o.y = f2bf(v.y - colsum[c + 1] * inv);
  o.z = f2bf(v.z - colsum[c + 2] * inv);
  o.w = f2bf(v.w - colsum[c + 3] * inv);
  *(ushort4*)(aggr_c + i) = o;
}

// ---------------- bf16 MFMA GEMM1: z1[V][512] = A[V][256] @ W1T^T + b1, + column stats ----------------
template <int K, int N>
__global__ __launch_bounds__(256) void gemm_kernel(
    const unsigned short* __restrict__ A, const unsigned short* __restrict__ BT,
    const float* __restrict__ bias, unsigned short* __restrict__ C,
    float* __restrict__ sumP, float* __restrict__ sqP) {
  __shared__ char lds[16384];
  const int t = threadIdx.x;
  const int lane = t & 63;
  const int wid = t >> 6;
  const int waveM = wid >> 1, waveN = wid & 1;
  const int rowBase = blockIdx.x * 128;
  const int colBase = blockIdx.y * 128;
  const int kw = lane >> 4;
  const int l15 = lane & 15;

  f32x4 acc[4][4];
#pragma unroll
  for (int m = 0; m < 4; ++m)
#pragma unroll
    for (int n = 0; n < 4; ++n) acc[m][n] = (f32x4){0.f, 0.f, 0.f, 0.f};

  for (int k0 = 0; k0 < K; k0 += 32) {
#pragma unroll
    for (int c = 0; c < 2; ++c) {
      int row = c * 64 + (t >> 2);
      int gslot = (t & 3) ^ ((row >> 1) & 3);
      const unsigned short* ga = A + (size_t)(rowBase + row) * K + k0 + gslot * 8;
      async16(ga, lds + c * 4096 + wid * 1024);
      const unsigned short* gb = BT + (size_t)(colBase + row) * K + k0 + gslot * 8;
      async16(gb, lds + 8192 + c * 4096 + wid * 1024);
    }
    __syncthreads();

    bf16x8 af[4], bfr[4];
#pragma unroll
    for (int f = 0; f < 4; ++f) {
      int rA = waveM * 64 + f * 16 + l15;
      af[f] = *(const bf16x8*)(lds + rA * 64 + ((kw ^ ((rA >> 1) & 3)) * 16));
      int rB = waveN * 64 + f * 16 + l15;
      bfr[f] = *(const bf16x8*)(lds + 8192 + rB * 64 + ((kw ^ ((rB >> 1) & 3)) * 16));
    }
#pragma unroll
    for (int m = 0; m < 4; ++m)
#pragma unroll
      for (int n = 0; n < 4; ++n)
        acc[m][n] = __builtin_amdgcn_mfma_f32_16x16x32_bf16(af[m], bfr[n], acc[m][n], 0, 0, 0);
    __syncthreads();
  }

  const int cB = colBase + waveN * 64;
  const int rB0 = rowBase + waveM * 64;
#pragma unroll
  for (int n = 0; n < 4; ++n) {
    int col = cB + n * 16 + l15;
    float bcol = bias[col];
    float psum = 0.f, psq = 0.f;
#pragma unroll
    for (int m = 0; m < 4; ++m) {
#pragma unroll
      for (int r = 0; r < 4; ++r) {
        float val = acc[m][n][r] + bcol;
        int row = rB0 + m * 16 + kw * 4 + r;
        C[(size_t)row * N + col] = f2bf(val);
        psum += val; psq += val * val;
      }
    }
    psum += __shfl_xor(psum, 16); psum += __shfl_xor(psum, 32);
    psq  += __shfl_xor(psq, 16);  psq  += __shfl_xor(psq, 32);
    if (kw == 0) {
      int prow = blockIdx.x * 2 + waveM;
      sumP[(size_t)prow * N + col] = psum;
      sqP[(size_t)prow * N + col] = psq;
    }
  }
}

// ---------------- GEMM2 with fused bn1+relu on A (reg-staged A), fp32 z2 out + stats ----------------
__global__ __launch_bounds__(256) void gemm2_kernel(
    const unsigned short* __restrict__ A /* raw z1 */, const unsigned short* __restrict__ BT,
    const float* __restrict__ scA, const float* __restrict__ shA,
    const float* __restrict__ bias, float* __restrict__ C /* fp32 z2 */,
    float* __restrict__ sumP, float* __restrict__ sqP) {
  const int K = 512, N = 256;
  __shared__ char lds[16384];
  const int t = threadIdx.x;
  const int lane = t & 63;
  const int wid = t >> 6;
  const int waveM = wid >> 1, waveN = wid & 1;
  const int rowBase = blockIdx.x * 128;
  const int colBase = blockIdx.y * 128;
  const int kw = lane >> 4;
  const int l15 = lane & 15;

  f32x4 acc[4][4];
#pragma unroll
  for (int m = 0; m < 4; ++m)
#pragma unroll
    for (int n = 0; n < 4; ++n) acc[m][n] = (f32x4){0.f, 0.f, 0.f, 0.f};

  for (int k0 = 0; k0 < K; k0 += 32) {
#pragma unroll
    for (int c = 0; c < 2; ++c) {
      int row = c * 64 + (t >> 2);
      int gslot = (t & 3) ^ ((row >> 1) & 3);
      const unsigned short* gb = BT + (size_t)(colBase + row) * K + k0 + gslot * 8;
      async16(gb, lds + 8192 + c * 4096 + wid * 1024);
    }
#pragma unroll
    for (int c = 0; c < 2; ++c) {
      int row = c * 64 + (t >> 2);
      int gslot = (t & 3) ^ ((row >> 1) & 3);
      int kk = k0 + gslot * 8;
      const unsigned short* ga = A + (size_t)(rowBase + row) * K + kk;
      ushort4 a0 = *(const ushort4*)ga;
      ushort4 a1 = *(const ushort4*)(ga + 4);
      float4 s0 = *(const float4*)(scA + kk);
      float4 s1 = *(const float4*)(scA + kk + 4);
      float4 h0 = *(const float4*)(shA + kk);
      float4 h1 = *(const float4*)(shA + kk + 4);
      bf16x8 o;
      o[0] = (short)f2bf(fmaxf(bf2f(a0.x) * s0.x + h0.x, 0.f));
      o[1] = (short)f2bf(fmaxf(bf2f(a0.y) * s0.y + h0.y, 0.f));
      o[2] = (short)f2bf(fmaxf(bf2f(a0.z) * s0.z + h0.z, 0.f));
      o[3] = (short)f2bf(fmaxf(bf2f(a0.w) * s0.w + h0.w, 0.f));
      o[4] = (short)f2bf(fmaxf(bf2f(a1.x) * s1.x + h1.x, 0.f));
      o[5] = (short)f2bf(fmaxf(bf2f(a1.y) * s1.y + h1.y, 0.f));
      o[6] = (short)f2bf(fmaxf(bf2f(a1.z) * s1.z + h1.z, 0.f));
      o[7] = (short)f2bf(fmaxf(bf2f(a1.w) * s1.w + h1.w, 0.f));
      *(bf16x8*)(lds + c * 4096 + wid * 1024 + (t & 63) * 16) = o;
    }
    __syncthreads();

    bf16x8 af[4], bfr[4];
#pragma unroll
    for (int f = 0; f < 4; ++f) {
      int rA = waveM * 64 + f * 16 + l15;
      af[f] = *(const bf16x8*)(lds + rA * 64 + ((kw ^ ((rA >> 1) & 3)) * 16));
      int rB = waveN * 64 + f * 16 + l15;
      bfr[f] = *(const bf16x8*)(lds + 8192 + rB * 64 + ((kw ^ ((rB >> 1) & 3)) * 16));
    }
#pragma unroll
    for (int m = 0; m < 4; ++m)
#pragma unroll
      for (int n = 0; n < 4; ++n)
        acc[m][n] = __builtin_amdgcn_mfma_f32_16x16x32_bf16(af[m], bfr[n], acc[m][n], 0, 0, 0);
    __syncthreads();
  }

  const int cB = colBase + waveN * 64;
  const int rB0 = rowBase + waveM * 64;
#pragma unroll
  for (int n = 0; n < 4; ++n) {
    int col = cB + n * 16 + l15;
    float bcol = bias[col];
    float psum = 0.f, psq = 0.f;
#pragma unroll
    for (int m = 0; m < 4; ++m) {
#pragma unroll
      for (int r = 0; r < 4; ++r) {
        float val = acc[m][n][r] + bcol;
        int row = rB0 + m * 16 + kw * 4 + r;
        C[(size_t)row * N + col] = val;
        psum += val; psq += val * val;
      }
    }
    psum += __shfl_xor(psum, 16); psum += __shfl_xor(psum, 32);
    psq  += __shfl_xor(psq, 16);  psq  += __shfl_xor(psq, 32);
    if (kw == 0) {
      int prow = blockIdx.x * 2 + waveM;
      sumP[(size_t)prow * N + col] = psum;
      sqP[(size_t)prow * N + col] = psq;
    }
  }
}

// ---------------- BN1 scale/shift ----------------
__global__ void finalize_kernel(const float* __restrict__ sumP, const float* __restrict__ sqP,
                                const float* __restrict__ g, const float* __restrict__ b,
                                float* __restrict__ scale, float* __restrict__ shift, int N) {
  __shared__ float ls[256], lq[256];
  int col = blockIdx.x, t = threadIdx.x;
  float s = 0.f, q = 0.f;
  for (int r = t; r < 1024; r += 256) {
    s += sumP[(size_t)r * N + col];
    q += sqP[(size_t)r * N + col];
  }
  ls[t] = s; lq[t] = q; __syncthreads();
  for (int off = 128; off > 0; off >>= 1) {
    if (t < off) { ls[t] += ls[t + off]; lq[t] += lq[t + off]; }
    __syncthreads();
  }
  if (t == 0) {
    float inv = 1.0f / 65536.0f;
    float mu = ls[0] * inv;
    float var = lq[0] * inv - mu * mu;
    float sc = g[col] * rsqrtf(var + 1e-5f);
    scale[col] = sc;
    shift[col] = b[col] - mu * sc;
  }
}

// ---------------- BN2: scale2 = g*rsqrt(var), shift2 = b (z2 stored centered), mu2 out ----------------
__global__ void finalize2_kernel(const float* __restrict__ sumP, const float* __restrict__ sqP,
                                 const float* __restrict__ g, const float* __restrict__ b,
                                 float* __restrict__ scale, float* __restrict__ shift,
                                 float* __restrict__ mu_out, int N) {
  __shared__ float ls[256], lq[256];
  int col = blockIdx.x, t = threadIdx.x;
  float s = 0.f, q = 0.f;
  for (int r = t; r < 1024; r += 256) {
    s += sumP[(size_t)r * N + col];
    q += sqP[(size_t)r * N + col];
  }
  ls[t] = s; lq[t] = q; __syncthreads();
  for (int off = 128; off > 0; off >>= 1) {
    if (t < off) { ls[t] += ls[t + off]; lq[t] += lq[t + off]; }
    __syncthreads();
  }
  if (t == 0) {
    float inv = 1.0f / 65536.0f;
    float mu = ls[0] * inv;
    float var = lq[0] * inv - mu * mu;
    scale[col] = g[col] * rsqrtf(var + 1e-5f);
    shift[col] = b[col];
    mu_out[col] = mu;
  }
}

// ---------------- center z2 columns + convert to bf16 ----------------
__global__ __launch_bounds__(256) void center2_kernel(const float* __restrict__ z2f,
                                                      const float* __restrict__ mu2,
                                                      unsigned short* __restrict__ z2c) {
  size_t i = ((size_t)blockIdx.x * 256 + threadIdx.x) * 4;
  int c = (int)(i & 255);
  float4 v = *(const float4*)(z2f + i);
  ushort4 o;
  o.x = f2bf(v.x - mu2[c + 0]);
  o.y = f2bf(v.y - mu2[c + 1]);
  o.z = f2bf(v.z - mu2[c + 2]);
  o.w = f2bf(v.w - mu2[c + 3]);
  *(ushort4*)(z2c + i) = o;
}

// ---------------- final: out = x; out[:,1:,:] += mask * (z2c*scale2 + shift2) ----------------
__global__ void final_out_kernel(const float* __restrict__ x, const unsigned short* __restrict__ z2c,
                                 const float* __restrict__ scale2, const float* __restrict__ shift2,
                                 const int* __restrict__ xmask, float* __restrict__ out) {
  int row = blockIdx.x;   // 0..256
  int b = blockIdx.y;     // 0..255
  int lane = threadIdx.x; // 0..63
  size_t off = ((size_t)b * 257 + row) * 256 + lane * 4;
  float4 xv = *(const float4*)(x + off);
  if (row > 0) {
    int v = b * 256 + (row - 1);
    float m = (float)xmask[v];
    ushort4 tv = *(const ushort4*)(z2c + (size_t)v * 256 + lane * 4);
    int c = lane * 4;
    xv.x += m * (bf2f(tv.x) * scale2[c + 0] + shift2[c + 0]);
    xv.y += m * (bf2f(tv.y) * scale2[c + 1] + shift2[c + 1]);
    xv.z += m * (bf2f(tv.z) * scale2[c + 2] + shift2[c + 2]);
    xv.w += m * (bf2f(tv.w) * scale2[c + 3] + shift2[c + 3]);
  }
  *(float4*)(out + off) = xv;
}

extern "C" void kernel_launch(void* const* d_in, const int* in_sizes, int n_in,
                              void* d_out, int out_size, void* d_ws, size_t ws_size,
                              hipStream_t stream) {
  const float* x    = (const float*)d_in[0];
  const float* ew   = (const float*)d_in[1];
  const float* bemb = (const float*)d_in[2];
  const float* W1   = (const float*)d_in[3];
  const float* b1   = (const float*)d_in[4];
  const float* g1   = (const float*)d_in[5];
  const float* bb1  = (const float*)d_in[6];
  const float* W2   = (const float*)d_in[7];
  const float* b2   = (const float*)d_in[8];
  const float* g2   = (const float*)d_in[9];
  const float* bb2  = (const float*)d_in[10];
  const float* eps  = (const float*)d_in[11];
  const int* xmask  = (const int*)d_in[12];
  const int* ei     = (const int*)d_in[13];
  const int* ea     = (const int*)d_in[14];
  float* out = (float*)d_out;

  char* ws = (char*)d_ws;
  size_t off = 0;
  auto alloc = [&](size_t bytes) {
    char* p = ws + off;
    off += (bytes + 255) & ~(size_t)255;
    return p;
  };
  unsigned short* W1T = (unsigned short*)alloc(5ull * 512 * 256 * 2);
  unsigned short* W2T = (unsigned short*)alloc(5ull * 256 * 512 * 2);
  int* counts = (int*)alloc(65536ull * 4);
  int* fill   = (int*)alloc(65536ull * 4);
  int* indptr = (int*)alloc(65537ull * 4);
  int* bsums  = (int*)alloc(256 * 4);
  int* boff   = (int*)alloc(256 * 4);
  int* csr    = (int*)alloc(327680ull * 4);
  float* scale1 = (float*)alloc(512 * 4);
  float* shift1 = (float*)alloc(512 * 4);
  float* scale2 = (float*)alloc(256 * 4);
  float* shift2 = (float*)alloc(256 * 4);
  float* colsum = (float*)alloc(256 * 4);
  float* mu2    = (float*)alloc(256 * 4);
  float* sumP = (float*)alloc(1024ull * 512 * 4);
  float* sqP  = (float*)alloc(1024ull * 512 * 4);
  float* aggr_f = (float*)alloc(65536ull * 256 * 4);   // reused as fp32 z2 scratch
  unsigned short* aggr_c = (unsigned short*)alloc(65536ull * 256 * 2);
  unsigned short* z1   = (unsigned short*)alloc(65536ull * 512 * 2);
  unsigned short* z2c  = (unsigned short*)alloc(65536ull * 256 * 2);
  (void)ws_size; (void)in_sizes; (void)n_in; (void)out_size;

  hipMemsetAsync(counts, 0, 65536ull * 4, stream);
  hipMemsetAsync(fill, 0, 65536ull * 4, stream);

  convert_weights_kernel<<<2560, 256, 0, stream>>>(W1, W2, W1T, W2T);
  hist_kernel<<<1280, 256, 0, stream>>>(ei, counts);
  scan1_kernel<<<256, 256, 0, stream>>>(counts, indptr, bsums);
  scan2_kernel<<<1, 256, 0, stream>>>(bsums, boff);
  scan3_kernel<<<256, 256, 0, stream>>>(indptr, boff);
  scatter_kernel<<<1280, 256, 0, stream>>>(ei, indptr, fill, csr);

  for (int i = 0; i < 5; ++i) {
    const float* bemb_l = bemb + (size_t)i * 3 * 16 * 256;
    if (i == 0)
      msg_kernel<true><<<16384, 256, 0, stream>>>(x, (const unsigned short*)nullptr, nullptr, nullptr,
                                                  indptr, csr, ei, ea, ew, bemb_l, eps, i, aggr_f);
    else
      msg_kernel<false><<<16384, 256, 0, stream>>>(x, z2c, scale2, shift2,
                                                   indptr, csr, ei, ea, ew, bemb_l, eps, i, aggr_f);
    hipMemsetAsync(colsum, 0, 256 * 4, stream);
    colsum_kernel<<<1024, 256, 0, stream>>>(aggr_f, colsum);
    center_kernel<<<16384, 256, 0, stream>>>(aggr_f, colsum, aggr_c);
    gemm_kernel<256, 512><<<dim3(512, 4), 256, 0, stream>>>(
        aggr_c, W1T + (size_t)i * 512 * 256, b1 + i * 512, z1, sumP, sqP);
    finalize_kernel<<<512, 256, 0, stream>>>(sumP, sqP, g1 + i * 512, bb1 + i * 512,
                                             scale1, shift1, 512);
    gemm2_kernel<<<dim3(512, 2), 256, 0, stream>>>(
        z1, W2T + (size_t)i * 256 * 512, scale1, shift1, b2 + i * 256, aggr_f, sumP, sqP);
    finalize2_kernel<<<256, 256, 0, stream>>>(sumP, sqP, g2 + i * 256, bb2 + i * 256,
                                              scale2, shift2, mu2, 256);
    center2_kernel<<<16384, 256, 0, stream>>>(aggr_f, mu2, z2c);
  }
  final_out_kernel<<<dim3(257, 256), 64, 0, stream>>>(x, z2c, scale2, shift2, xmask, out);
}

// Round 8
// 1445.364 us; speedup vs baseline: 1.0090x; 1.0090x over previous
//
#include <hip/hip_runtime.h>

#define E_EDGES 262144
#define V_NODES 65536
#define D_DIM   256

typedef short bf16x8 __attribute__((ext_vector_type(8)));
typedef float f32x4  __attribute__((ext_vector_type(4)));

__device__ __forceinline__ unsigned short f2bf(float f) {
  union { float f; unsigned u; } x; x.f = f;
  unsigned r = x.u + 0x7FFFu + ((x.u >> 16) & 1u);
  return (unsigned short)(r >> 16);
}
__device__ __forceinline__ float bf2f(unsigned short h) {
  union { unsigned u; float f; } x; x.u = ((unsigned)h) << 16;
  return x.f;
}
__device__ __forceinline__ void async16(const void* g, void* l) {
  __builtin_amdgcn_global_load_lds(
      (const __attribute__((address_space(1))) unsigned*)g,
      (__attribute__((address_space(3))) unsigned*)l, 16, 0, 0);
}

// ---------------- weight convert + transpose to bf16 [N][K] ----------------
__global__ __launch_bounds__(256) void convert_weights_kernel(
    const float* __restrict__ W1, const float* __restrict__ W2,
    unsigned short* __restrict__ W1T, unsigned short* __restrict__ W2T) {
  int idx = blockIdx.x * 256 + threadIdx.x;           // 0 .. 655359
  {
    int k = idx & 255, n = (idx >> 8) & 511, i = idx >> 17;
    W1T[idx] = f2bf(W1[((size_t)(i * 256 + k)) * 512 + n]);
  }
  {
    int k = idx & 511, n = (idx >> 9) & 255, i = idx >> 17;
    W2T[idx] = f2bf(W2[((size_t)(i * 512 + k)) * 256 + n]);
  }
}

// ---------------- CSR build (by destination) ----------------
__global__ void hist_kernel(const int* __restrict__ ei, int* __restrict__ counts) {
  int e = blockIdx.x * 256 + threadIdx.x;
  int d = (e < E_EDGES) ? ei[E_EDGES + e] : (e - E_EDGES);
  atomicAdd(&counts[d], 1);
}
__global__ void scan1_kernel(const int* __restrict__ counts, int* __restrict__ indptr,
                             int* __restrict__ bsums) {
  __shared__ int s[256];
  int t = threadIdx.x, b = blockIdx.x;
  int v = counts[b * 256 + t];
  s[t] = v; __syncthreads();
  for (int off = 1; off < 256; off <<= 1) {
    int add = (t >= off) ? s[t - off] : 0;
    __syncthreads();
    s[t] += add;
    __syncthreads();
  }
  indptr[b * 256 + t] = s[t] - v;
  if (t == 255) bsums[b] = s[255];
}
__global__ void scan2_kernel(const int* __restrict__ bsums, int* __restrict__ boff) {
  __shared__ int s[256];
  int t = threadIdx.x;
  int v = bsums[t];
  s[t] = v; __syncthreads();
  for (int off = 1; off < 256; off <<= 1) {
    int add = (t >= off) ? s[t - off] : 0;
    __syncthreads();
    s[t] += add;
    __syncthreads();
  }
  boff[t] = s[t] - v;
}
__global__ void scan3_kernel(int* __restrict__ indptr, const int* __restrict__ boff) {
  int t = threadIdx.x, b = blockIdx.x;
  indptr[b * 256 + t] += boff[b];
  if (b == 0 && t == 0) indptr[V_NODES] = E_EDGES + V_NODES;
}
__global__ void scatter_kernel(const int* __restrict__ ei, const int* __restrict__ indptr,
                               int* __restrict__ fill, int* __restrict__ csr_eid) {
  int e = blockIdx.x * 256 + threadIdx.x;
  int d = (e < E_EDGES) ? ei[E_EDGES + e] : (e - E_EDGES);
  int pos = indptr[d] + atomicAdd(&fill[d], 1);
  csr_eid[pos] = e;
}

// ---------------- message passing v3: 2-deep gather double-buffer ----------------
// aggr = (1+eps)*h + sum relu(h[src]+eemb)*w   (fp32 out)
// h = x (L0) or relu(z2c*scale2 + shift2), z2c centered bf16, shift2 = bb2.
template <bool L0>
struct EdgeBuf {
  float4 hrawf;      // L0: raw x row chunk
  ushort4 hrawb;     // !L0: raw bf16 row chunk
  float4 e0, e1, e2;
  float w;
};

template <bool L0>
__device__ __forceinline__ void resolve_and_issue(
    int p, int c0, const int* __restrict__ csr_eid, const int* __restrict__ ei,
    const int* __restrict__ ea, const float* __restrict__ ew,
    const float* __restrict__ x, const unsigned short* __restrict__ hprev,
    const float* __restrict__ bemb, EdgeBuf<L0>& B) {
  int eid = csr_eid[p];
  int s, a0, a1, a2;
  if (eid < E_EDGES) {
    s = ei[eid];
    a0 = ea[eid * 3]; a1 = ea[eid * 3 + 1]; a2 = ea[eid * 3 + 2];
    B.w = ew[eid];
  } else {
    s = eid - E_EDGES; a0 = 5; a1 = 7; a2 = 0; B.w = 1.0f;
  }
  if (L0) {
    const float* pp = x + ((size_t)((s >> 8) * 257 + (s & 255) + 1)) * 256 + c0;
    B.hrawf = *(const float4*)pp;
  } else {
    B.hrawb = *(const ushort4*)(hprev + (size_t)s * 256 + c0);
  }
  B.e0 = *(const float4*)(bemb + (size_t)(a0) * 256 + c0);
  B.e1 = *(const float4*)(bemb + (size_t)(16 + a1) * 256 + c0);
  B.e2 = *(const float4*)(bemb + (size_t)(32 + a2) * 256 + c0);
}

template <bool L0>
__global__ __launch_bounds__(256) void msg_kernel(
    const float* __restrict__ x, const unsigned short* __restrict__ hprev,
    const float* __restrict__ scale2, const float* __restrict__ shift2,
    const int* __restrict__ indptr, const int* __restrict__ csr_eid,
    const int* __restrict__ ei, const int* __restrict__ ea, const float* __restrict__ ew,
    const float* __restrict__ bemb, const float* __restrict__ eps_param, int layer,
    float* __restrict__ aggr_f) {
  int wid = threadIdx.x >> 6;
  int lane = threadIdx.x & 63;
  int v = blockIdx.x * 4 + wid;
  int c0 = lane * 4;
  float ep = 1.0f + eps_param[layer];

  float sc[4], sh[4];
  if (!L0) {
#pragma unroll
    for (int j = 0; j < 4; ++j) { sc[j] = scale2[c0 + j]; sh[j] = shift2[c0 + j]; }
  }

  // own-node h (issue early; consumed at the end)
  float hv[4];
  if (L0) {
    const float* p = x + ((size_t)((v >> 8) * 257 + (v & 255) + 1)) * 256 + c0;
    float4 tv = *(const float4*)p;
    hv[0] = tv.x; hv[1] = tv.y; hv[2] = tv.z; hv[3] = tv.w;
  } else {
    ushort4 tv = *(const ushort4*)(hprev + (size_t)v * 256 + c0);
    hv[0] = fmaxf(bf2f(tv.x) * sc[0] + sh[0], 0.f);
    hv[1] = fmaxf(bf2f(tv.y) * sc[1] + sh[1], 0.f);
    hv[2] = fmaxf(bf2f(tv.z) * sc[2] + sh[2], 0.f);
    hv[3] = fmaxf(bf2f(tv.w) * sc[3] + sh[3], 0.f);
  }

  float acc[4] = { 0.f, 0.f, 0.f, 0.f };

  int beg = indptr[v], end = indptr[v + 1];
  EdgeBuf<L0> cur, nxt;
  resolve_and_issue<L0>(beg, c0, csr_eid, ei, ea, ew, x, hprev, bemb, cur);

  for (int p = beg; p < end; ++p) {
    // issue NEXT edge's loads first (overlaps current edge's wait)
    if (p + 1 < end)
      resolve_and_issue<L0>(p + 1, c0, csr_eid, ei, ea, ew, x, hprev, bemb, nxt);

    float hs[4];
    if (L0) {
      hs[0] = cur.hrawf.x; hs[1] = cur.hrawf.y; hs[2] = cur.hrawf.z; hs[3] = cur.hrawf.w;
    } else {
      hs[0] = fmaxf(bf2f(cur.hrawb.x) * sc[0] + sh[0], 0.f);
      hs[1] = fmaxf(bf2f(cur.hrawb.y) * sc[1] + sh[1], 0.f);
      hs[2] = fmaxf(bf2f(cur.hrawb.z) * sc[2] + sh[2], 0.f);
      hs[3] = fmaxf(bf2f(cur.hrawb.w) * sc[3] + sh[3], 0.f);
    }
    acc[0] += fmaxf(hs[0] + cur.e0.x + cur.e1.x + cur.e2.x, 0.f) * cur.w;
    acc[1] += fmaxf(hs[1] + cur.e0.y + cur.e1.y + cur.e2.y, 0.f) * cur.w;
    acc[2] += fmaxf(hs[2] + cur.e0.z + cur.e1.z + cur.e2.z, 0.f) * cur.w;
    acc[3] += fmaxf(hs[3] + cur.e0.w + cur.e1.w + cur.e2.w, 0.f) * cur.w;
    cur = nxt;
  }

  float4 o;
  o.x = acc[0] + ep * hv[0];
  o.y = acc[1] + ep * hv[1];
  o.z = acc[2] + ep * hv[2];
  o.w = acc[3] + ep * hv[3];
  *(float4*)(aggr_f + (size_t)v * 256 + c0) = o;
}

// ---------------- column sums of fp32 aggr (for BN-invariant centering) ----------------
__global__ __launch_bounds__(256) void colsum_kernel(const float* __restrict__ aggr_f,
                                                     float* __restrict__ colsum) {
  int t = threadIdx.x;
  size_t base = (size_t)blockIdx.x * 64 * 256 + t;
  float s = 0.f;
#pragma unroll
  for (int r = 0; r < 64; ++r) s += aggr_f[base + (size_t)r * 256];
  atomicAdd(&colsum[t], s);
}

// ---------------- GEMM1: z1 = bf16(aggr-colmean) @ W1T^T + b1 (center fused in A-staging) ----------------
__global__ __launch_bounds__(256) void gemm1_kernel(
    const float* __restrict__ A /* fp32 aggr */, const unsigned short* __restrict__ BT,
    const float* __restrict__ colsum, const float* __restrict__ bias,
    unsigned short* __restrict__ C, float* __restrict__ sumP, float* __restrict__ sqP) {
  const int K = 256, N = 512;
  __shared__ char lds[16384];
  const int t = threadIdx.x;
  const int lane = t & 63;
  const int wid = t >> 6;
  const int waveM = wid >> 1, waveN = wid & 1;
  const int rowBase = blockIdx.x * 128;
  const int colBase = blockIdx.y * 128;
  const int kw = lane >> 4;
  const int l15 = lane & 15;
  const float inv = 1.0f / 65536.0f;

  f32x4 acc[4][4];
#pragma unroll
  for (int m = 0; m < 4; ++m)
#pragma unroll
    for (int n = 0; n < 4; ++n) acc[m][n] = (f32x4){0.f, 0.f, 0.f, 0.f};

  for (int k0 = 0; k0 < K; k0 += 32) {
    // B: async gload_lds
#pragma unroll
    for (int c = 0; c < 2; ++c) {
      int row = c * 64 + (t >> 2);
      int gslot = (t & 3) ^ ((row >> 1) & 3);
      const unsigned short* gb = BT + (size_t)(colBase + row) * K + k0 + gslot * 8;
      async16(gb, lds + 8192 + c * 4096 + wid * 1024);
    }
    // A: reg-stage fp32 -> centered bf16
#pragma unroll
    for (int c = 0; c < 2; ++c) {
      int row = c * 64 + (t >> 2);
      int gslot = (t & 3) ^ ((row >> 1) & 3);
      int kk = k0 + gslot * 8;
      const float* ga = A + (size_t)(rowBase + row) * K + kk;
      float4 a0 = *(const float4*)ga;
      float4 a1 = *(const float4*)(ga + 4);
      float4 m0 = *(const float4*)(colsum + kk);
      float4 m1 = *(const float4*)(colsum + kk + 4);
      bf16x8 o;
      o[0] = (short)f2bf(a0.x - m0.x * inv);
      o[1] = (short)f2bf(a0.y - m0.y * inv);
      o[2] = (short)f2bf(a0.z - m0.z * inv);
      o[3] = (short)f2bf(a0.w - m0.w * inv);
      o[4] = (short)f2bf(a1.x - m1.x * inv);
      o[5] = (short)f2bf(a1.y - m1.y * inv);
      o[6] = (short)f2bf(a1.z - m1.z * inv);
      o[7] = (short)f2bf(a1.w - m1.w * inv);
      *(bf16x8*)(lds + c * 4096 + wid * 1024 + (t & 63) * 16) = o;
    }
    __syncthreads();

    bf16x8 af[4], bfr[4];
#pragma unroll
    for (int f = 0; f < 4; ++f) {
      int rA = waveM * 64 + f * 16 + l15;
      af[f] = *(const bf16x8*)(lds + rA * 64 + ((kw ^ ((rA >> 1) & 3)) * 16));
      int rB = waveN * 64 + f * 16 + l15;
      bfr[f] = *(const bf16x8*)(lds + 8192 + rB * 64 + ((kw ^ ((rB >> 1) & 3)) * 16));
    }
#pragma unroll
    for (int m = 0; m < 4; ++m)
#pragma unroll
      for (int n = 0; n < 4; ++n)
        acc[m][n] = __builtin_amdgcn_mfma_f32_16x16x32_bf16(af[m], bfr[n], acc[m][n], 0, 0, 0);
    __syncthreads();
  }

  const int cB = colBase + waveN * 64;
  const int rB0 = rowBase + waveM * 64;
#pragma unroll
  for (int n = 0; n < 4; ++n) {
    int col = cB + n * 16 + l15;
    float bcol = bias[col];
    float psum = 0.f, psq = 0.f;
#pragma unroll
    for (int m = 0; m < 4; ++m) {
#pragma unroll
      for (int r = 0; r < 4; ++r) {
        float val = acc[m][n][r] + bcol;
        int row = rB0 + m * 16 + kw * 4 + r;
        C[(size_t)row * N + col] = f2bf(val);
        psum += val; psq += val * val;
      }
    }
    psum += __shfl_xor(psum, 16); psum += __shfl_xor(psum, 32);
    psq  += __shfl_xor(psq, 16);  psq  += __shfl_xor(psq, 32);
    if (kw == 0) {
      int prow = blockIdx.x * 2 + waveM;
      sumP[(size_t)prow * N + col] = psum;
      sqP[(size_t)prow * N + col] = psq;
    }
  }
}

// ---------------- GEMM2 with fused bn1+relu on A (reg-staged A), fp32 z2 out + stats ----------------
__global__ __launch_bounds__(256) void gemm2_kernel(
    const unsigned short* __restrict__ A /* raw z1 */, const unsigned short* __restrict__ BT,
    const float* __restrict__ scA, const float* __restrict__ shA,
    const float* __restrict__ bias, float* __restrict__ C /* fp32 z2 */,
    float* __restrict__ sumP, float* __restrict__ sqP) {
  const int K = 512, N = 256;
  __shared__ char lds[16384];
  const int t = threadIdx.x;
  const int lane = t & 63;
  const int wid = t >> 6;
  const int waveM = wid >> 1, waveN = wid & 1;
  const int rowBase = blockIdx.x * 128;
  const int colBase = blockIdx.y * 128;
  const int kw = lane >> 4;
  const int l15 = lane & 15;

  f32x4 acc[4][4];
#pragma unroll
  for (int m = 0; m < 4; ++m)
#pragma unroll
    for (int n = 0; n < 4; ++n) acc[m][n] = (f32x4){0.f, 0.f, 0.f, 0.f};

  for (int k0 = 0; k0 < K; k0 += 32) {
#pragma unroll
    for (int c = 0; c < 2; ++c) {
      int row = c * 64 + (t >> 2);
      int gslot = (t & 3) ^ ((row >> 1) & 3);
      const unsigned short* gb = BT + (size_t)(colBase + row) * K + k0 + gslot * 8;
      async16(gb, lds + 8192 + c * 4096 + wid * 1024);
    }
#pragma unroll
    for (int c = 0; c < 2; ++c) {
      int row = c * 64 + (t >> 2);
      int gslot = (t & 3) ^ ((row >> 1) & 3);
      int kk = k0 + gslot * 8;
      const unsigned short* ga = A + (size_t)(rowBase + row) * K + kk;
      ushort4 a0 = *(const ushort4*)ga;
      ushort4 a1 = *(const ushort4*)(ga + 4);
      float4 s0 = *(const float4*)(scA + kk);
      float4 s1 = *(const float4*)(scA + kk + 4);
      float4 h0 = *(const float4*)(shA + kk);
      float4 h1 = *(const float4*)(shA + kk + 4);
      bf16x8 o;
      o[0] = (short)f2bf(fmaxf(bf2f(a0.x) * s0.x + h0.x, 0.f));
      o[1] = (short)f2bf(fmaxf(bf2f(a0.y) * s0.y + h0.y, 0.f));
      o[2] = (short)f2bf(fmaxf(bf2f(a0.z) * s0.z + h0.z, 0.f));
      o[3] = (short)f2bf(fmaxf(bf2f(a0.w) * s0.w + h0.w, 0.f));
      o[4] = (short)f2bf(fmaxf(bf2f(a1.x) * s1.x + h1.x, 0.f));
      o[5] = (short)f2bf(fmaxf(bf2f(a1.y) * s1.y + h1.y, 0.f));
      o[6] = (short)f2bf(fmaxf(bf2f(a1.z) * s1.z + h1.z, 0.f));
      o[7] = (short)f2bf(fmaxf(bf2f(a1.w) * s1.w + h1.w, 0.f));
      *(bf16x8*)(lds + c * 4096 + wid * 1024 + (t & 63) * 16) = o;
    }
    __syncthreads();

    bf16x8 af[4], bfr[4];
#pragma unroll
    for (int f = 0; f < 4; ++f) {
      int rA = waveM * 64 + f * 16 + l15;
      af[f] = *(const bf16x8*)(lds + rA * 64 + ((kw ^ ((rA >> 1) & 3)) * 16));
      int rB = waveN * 64 + f * 16 + l15;
      bfr[f] = *(const bf16x8*)(lds + 8192 + rB * 64 + ((kw ^ ((rB >> 1) & 3)) * 16));
    }
#pragma unroll
    for (int m = 0; m < 4; ++m)
#pragma unroll
      for (int n = 0; n < 4; ++n)
        acc[m][n] = __builtin_amdgcn_mfma_f32_16x16x32_bf16(af[m], bfr[n], acc[m][n], 0, 0, 0);
    __syncthreads();
  }

  const int cB = colBase + waveN * 64;
  const int rB0 = rowBase + waveM * 64;
#pragma unroll
  for (int n = 0; n < 4; ++n) {
    int col = cB + n * 16 + l15;
    float bcol = bias[col];
    float psum = 0.f, psq = 0.f;
#pragma unroll
    for (int m = 0; m < 4; ++m) {
#pragma unroll
      for (int r = 0; r < 4; ++r) {
        float val = acc[m][n][r] + bcol;
        int row = rB0 + m * 16 + kw * 4 + r;
        C[(size_t)row * N + col] = val;
        psum += val; psq += val * val;
      }
    }
    psum += __shfl_xor(psum, 16); psum += __shfl_xor(psum, 32);
    psq  += __shfl_xor(psq, 16);  psq  += __shfl_xor(psq, 32);
    if (kw == 0) {
      int prow = blockIdx.x * 2 + waveM;
      sumP[(size_t)prow * N + col] = psum;
      sqP[(size_t)prow * N + col] = psq;
    }
  }
}

// ---------------- BN1 scale/shift ----------------
__global__ void finalize_kernel(const float* __restrict__ sumP, const float* __restrict__ sqP,
                                const float* __restrict__ g, const float* __restrict__ b,
                                float* __restrict__ scale, float* __restrict__ shift, int N) {
  __shared__ float ls[256], lq[256];
  int col = blockIdx.x, t = threadIdx.x;
  float s = 0.f, q = 0.f;
  for (int r = t; r < 1024; r += 256) {
    s += sumP[(size_t)r * N + col];
    q += sqP[(size_t)r * N + col];
  }
  ls[t] = s; lq[t] = q; __syncthreads();
  for (int off = 128; off > 0; off >>= 1) {
    if (t < off) { ls[t] += ls[t + off]; lq[t] += lq[t + off]; }
    __syncthreads();
  }
  if (t == 0) {
    float inv = 1.0f / 65536.0f;
    float mu = ls[0] * inv;
    float var = lq[0] * inv - mu * mu;
    float sc = g[col] * rsqrtf(var + 1e-5f);
    scale[col] = sc;
    shift[col] = b[col] - mu * sc;
  }
}

// ---------------- BN2: scale2 = g*rsqrt(var), shift2 = b (z2 stored centered), mu2 out ----------------
__global__ void finalize2_kernel(const float* __restrict__ sumP, const float* __restrict__ sqP,
                                 const float* __restrict__ g, const float* __restrict__ b,
                                 float* __restrict__ scale, float* __restrict__ shift,
                                 float* __restrict__ mu_out, int N) {
  __shared__ float ls[256], lq[256];
  int col = blockIdx.x, t = threadIdx.x;
  float s = 0.f, q = 0.f;
  for (int r = t; r < 1024; r += 256) {
    s += sumP[(size_t)r * N + col];
    q += sqP[(size_t)r * N + col];
  }
  ls[t] = s; lq[t] = q; __syncthreads();
  for (int off = 128; off > 0; off >>= 1) {
    if (t < off) { ls[t] += ls[t + off]; lq[t] += lq[t + off]; }
    __syncthreads();
  }
  if (t == 0) {
    float inv = 1.0f / 65536.0f;
    float mu = ls[0] * inv;
    float var = lq[0] * inv - mu * mu;
    scale[col] = g[col] * rsqrtf(var + 1e-5f);
    shift[col] = b[col];
    mu_out[col] = mu;
  }
}

// ---------------- center z2 columns + convert to bf16 (layers 0..3 only) ----------------
__global__ __launch_bounds__(256) void center2_kernel(const float* __restrict__ z2f,
                                                      const float* __restrict__ mu2,
                                                      unsigned short* __restrict__ z2c) {
  size_t i = ((size_t)blockIdx.x * 256 + threadIdx.x) * 4;
  int c = (int)(i & 255);
  float4 v = *(const float4*)(z2f + i);
  ushort4 o;
  o.x = f2bf(v.x - mu2[c + 0]);
  o.y = f2bf(v.y - mu2[c + 1]);
  o.z = f2bf(v.z - mu2[c + 2]);
  o.w = f2bf(v.w - mu2[c + 3]);
  *(ushort4*)(z2c + i) = o;
}

// ---------------- final: out = x; out[:,1:,:] += mask * ((z2f-mu2)*scale2 + shift2) ----------------
__global__ void final_out_kernel(const float* __restrict__ x, const float* __restrict__ z2f,
                                 const float* __restrict__ mu2,
                                 const float* __restrict__ scale2, const float* __restrict__ shift2,
                                 const int* __restrict__ xmask, float* __restrict__ out) {
  int row = blockIdx.x;   // 0..256
  int b = blockIdx.y;     // 0..255
  int lane = threadIdx.x; // 0..63
  size_t off = ((size_t)b * 257 + row) * 256 + lane * 4;
  float4 xv = *(const float4*)(x + off);
  if (row > 0) {
    int v = b * 256 + (row - 1);
    float m = (float)xmask[v];
    float4 tv = *(const float4*)(z2f + (size_t)v * 256 + lane * 4);
    int c = lane * 4;
    xv.x += m * ((tv.x - mu2[c + 0]) * scale2[c + 0] + shift2[c + 0]);
    xv.y += m * ((tv.y - mu2[c + 1]) * scale2[c + 1] + shift2[c + 1]);
    xv.z += m * ((tv.z - mu2[c + 2]) * scale2[c + 2] + shift2[c + 2]);
    xv.w += m * ((tv.w - mu2[c + 3]) * scale2[c + 3] + shift2[c + 3]);
  }
  *(float4*)(out + off) = xv;
}

extern "C" void kernel_launch(void* const* d_in, const int* in_sizes, int n_in,
                              void* d_out, int out_size, void* d_ws, size_t ws_size,
                              hipStream_t stream) {
  const float* x    = (const float*)d_in[0];
  const float* ew   = (const float*)d_in[1];
  const float* bemb = (const float*)d_in[2];
  const float* W1   = (const float*)d_in[3];
  const float* b1   = (const float*)d_in[4];
  const float* g1   = (const float*)d_in[5];
  const float* bb1  = (const float*)d_in[6];
  const float* W2   = (const float*)d_in[7];
  const float* b2   = (const float*)d_in[8];
  const float* g2   = (const float*)d_in[9];
  const float* bb2  = (const float*)d_in[10];
  const float* eps  = (const float*)d_in[11];
  const int* xmask  = (const int*)d_in[12];
  const int* ei     = (const int*)d_in[13];
  const int* ea     = (const int*)d_in[14];
  float* out = (float*)d_out;

  char* ws = (char*)d_ws;
  size_t off = 0;
  auto alloc = [&](size_t bytes) {
    char* p = ws + off;
    off += (bytes + 255) & ~(size_t)255;
    return p;
  };
  unsigned short* W1T = (unsigned short*)alloc(5ull * 512 * 256 * 2);
  unsigned short* W2T = (unsigned short*)alloc(5ull * 256 * 512 * 2);
  int* counts = (int*)alloc(65536ull * 4);
  int* fill   = (int*)alloc(65536ull * 4);
  int* indptr = (int*)alloc(65537ull * 4);
  int* bsums  = (int*)alloc(256 * 4);
  int* boff   = (int*)alloc(256 * 4);
  int* csr    = (int*)alloc(327680ull * 4);
  float* scale1 = (float*)alloc(512 * 4);
  float* shift1 = (float*)alloc(512 * 4);
  float* scale2 = (float*)alloc(256 * 4);
  float* shift2 = (float*)alloc(256 * 4);
  float* colsum = (float*)alloc(256 * 4);
  float* mu2    = (float*)alloc(256 * 4);
  float* sumP = (float*)alloc(1024ull * 512 * 4);
  float* sqP  = (float*)alloc(1024ull * 512 * 4);
  float* aggr_f = (float*)alloc(65536ull * 256 * 4);   // aggr, then reused as fp32 z2
  unsigned short* z1   = (unsigned short*)alloc(65536ull * 512 * 2);
  unsigned short* z2c  = (unsigned short*)alloc(65536ull * 256 * 2);
  (void)ws_size; (void)in_sizes; (void)n_in; (void)out_size;

  hipMemsetAsync(counts, 0, 65536ull * 4, stream);
  hipMemsetAsync(fill, 0, 65536ull * 4, stream);

  convert_weights_kernel<<<2560, 256, 0, stream>>>(W1, W2, W1T, W2T);
  hist_kernel<<<1280, 256, 0, stream>>>(ei, counts);
  scan1_kernel<<<256, 256, 0, stream>>>(counts, indptr, bsums);
  scan2_kernel<<<1, 256, 0, stream>>>(bsums, boff);
  scan3_kernel<<<256, 256, 0, stream>>>(indptr, boff);
  scatter_kernel<<<1280, 256, 0, stream>>>(ei, indptr, fill, csr);

  for (int i = 0; i < 5; ++i) {
    const float* bemb_l = bemb + (size_t)i * 3 * 16 * 256;
    if (i == 0)
      msg_kernel<true><<<16384, 256, 0, stream>>>(x, (const unsigned short*)nullptr, nullptr, nullptr,
                                                  indptr, csr, ei, ea, ew, bemb_l, eps, i, aggr_f);
    else
      msg_kernel<false><<<16384, 256, 0, stream>>>(x, z2c, scale2, shift2,
                                                   indptr, csr, ei, ea, ew, bemb_l, eps, i, aggr_f);
    hipMemsetAsync(colsum, 0, 256 * 4, stream);
    colsum_kernel<<<1024, 256, 0, stream>>>(aggr_f, colsum);
    gemm1_kernel<<<dim3(512, 4), 256, 0, stream>>>(
        aggr_f, W1T + (size_t)i * 512 * 256, colsum, b1 + i * 512, z1, sumP, sqP);
    finalize_kernel<<<512, 256, 0, stream>>>(sumP, sqP, g1 + i * 512, bb1 + i * 512,
                                             scale1, shift1, 512);
    gemm2_kernel<<<dim3(512, 2), 256, 0, stream>>>(
        z1, W2T + (size_t)i * 256 * 512, scale1, shift1, b2 + i * 256, aggr_f, sumP, sqP);
    finalize2_kernel<<<256, 256, 0, stream>>>(sumP, sqP, g2 + i * 256, bb2 + i * 256,
                                              scale2, shift2, mu2, 256);
    if (i != 4)
      center2_kernel<<<16384, 256, 0, stream>>>(aggr_f, mu2, z2c);
  }
  final_out_kernel<<<dim3(257, 256), 64, 0, stream>>>(x, aggr_f, mu2, scale2, shift2, xmask, out);
}